// Round 8
// baseline (29316.461 us; speedup 1.0000x reference)
//
#include <hip/hip_runtime.h>
#include <math.h>

#define HID   256
#define TLEN  512
#define BB    32            // batch per block
#define NTHR  1024          // 16 waves, 1 block/CU, 4 waves/SIMD

typedef __attribute__((ext_vector_type(8))) short short8;
typedef __attribute__((ext_vector_type(4))) float f32x4;

static __device__ __forceinline__ unsigned short f2bf_rne(float x) {
    unsigned int u = __float_as_uint(x);
    unsigned int r = (u + 0x7FFFu + ((u >> 16) & 1u)) >> 16;
    return (unsigned short)r;
}
static __device__ __forceinline__ float bf2f(unsigned short h) {
    return __uint_as_float(((unsigned int)h) << 16);
}
static __device__ __forceinline__ float sigf(float x) {
    return 1.0f / (1.0f + __expf(-x));
}
static __device__ __forceinline__ float tanhf_fast(float x) {
    return 1.0f - 2.0f / (1.0f + __expf(2.0f * x));
}

__global__ __launch_bounds__(NTHR, 4) void lstm_mfma7(
    const float* __restrict__ x,      // (B,1,1)
    const float* __restrict__ W_ih,   // (1024,)
    const float* __restrict__ W_hh,   // (1024,256) row-major fp32 — read directly
    const float* __restrict__ b_ih,   // (1024,)
    const float* __restrict__ b_hh,   // (1024,)
    const float* __restrict__ W_fc,   // (256,)
    const float* __restrict__ b_fc,   // (1,)
    float* __restrict__ out)          // (B, 512)
{
    const int tid  = threadIdx.x;
    const int wave = tid >> 6;        // 0..15 : owns j-slice [wave*16, wave*16+16)
    const int lane = tid & 63;
    const int l15  = lane & 15;
    const int l4   = lane >> 4;
    const int bbase = blockIdx.x * BB;

    // h planes in MFMA A-fragment order, double-buffered:
    // tile (m,kc) at [(m*8+kc)*512 ..]; element (row,kw) at lane'=row+16*(kw>>3), elem=kw&7
    __shared__ unsigned short hhi[2][16 * 512];   // 2 x 16 KiB
    __shared__ unsigned short hlo[2][16 * 512];   // 2 x 16 KiB
    __shared__ float dpart[16][BB];
    __shared__ float inp_s[BB];

    for (int i = tid; i < 16 * 512; i += NTHR) { hhi[0][i] = 0; hlo[0][i] = 0; }
    if (tid < BB) inp_s[tid] = x[bbase + tid];

    // per-lane constants: gate row g = q*256 + wave*16 + l15
    float biasv[4], wihv[4];
    #pragma unroll
    for (int q = 0; q < 4; ++q) {
        int g = 256 * q + 16 * wave + l15;
        biasv[q] = b_ih[g] + b_hh[g];
        wihv[q]  = W_ih[g];
    }
    const float wfc = W_fc[16 * wave + l15];
    const float bfc = b_fc[0];

    // per-lane weight source base: B-frag row = 16*gt + l15, col window = kc*32 + l4*8
    // gt = q*16 + wave  ->  row = 256*q... no: 16*(q*16+wave) + l15 = 256q + 16wave + l15
    // src(q,kc) = W_hh + (256q + 16wave + l15)*HID + kc*32 + l4*8
    const float* __restrict__ wrow = W_hh + (size_t)(16 * wave + l15) * HID + l4 * 8;

    // h-write address (step-invariant parts): j = wave*16+l15
    const int kc_w  = wave >> 1;                       // j>>5
    const int kwhi  = (wave & 1) * 2 + (l15 >> 3);     // (j&31)>>3
    const int elemw = l15 & 7;

    float c_r[2][4];
    #pragma unroll
    for (int m = 0; m < 2; ++m)
        #pragma unroll
        for (int r = 0; r < 4; ++r) c_r[m][r] = 0.0f;

    __syncthreads();

    #pragma unroll 1
    for (int t = 0; t < TLEN; ++t) {
        const int p = t & 1;

        // ---- acc init: bias + d*W_ih ----
        f32x4 acc[2][4];
        {
            float dv[2][4];
            #pragma unroll
            for (int m = 0; m < 2; ++m)
                #pragma unroll
                for (int r = 0; r < 4; ++r)
                    dv[m][r] = inp_s[16 * m + 4 * l4 + r];
            #pragma unroll
            for (int m = 0; m < 2; ++m)
                #pragma unroll
                for (int q = 0; q < 4; ++q)
                    #pragma unroll
                    for (int r = 0; r < 4; ++r)
                        acc[m][q][r] = fmaf(dv[m][r], wihv[q], biasv[q]);
        }

        // ---- MFMA: gates += h @ W_hh^T (3-term split bf16, weights from d_in fp32) ----
        #pragma unroll
        for (int kc = 0; kc < 8; ++kc) {
            short8 ahi[2], alo[2];
            #pragma unroll
            for (int m = 0; m < 2; ++m) {
                int aoff = (m * 8 + kc) * 512 + lane * 8;
                ahi[m] = *(const short8*)&hhi[p][aoff];
                alo[m] = *(const short8*)&hlo[p][aoff];
            }
            #pragma unroll
            for (int q = 0; q < 4; ++q) {
                const float* src = wrow + (size_t)q * 256 * HID + kc * 32;
                float4 wa = *(const float4*)src;
                float4 wb = *(const float4*)(src + 4);
                float ff[8] = {wa.x, wa.y, wa.z, wa.w, wb.x, wb.y, wb.z, wb.w};
                short8 bhi, blo;
                #pragma unroll
                for (int e = 0; e < 8; ++e) {
                    unsigned int u = __float_as_uint(ff[e]);
                    bhi[e] = (short)(u >> 16);
                    float res = ff[e] - __uint_as_float(u & 0xffff0000u);
                    blo[e] = (short)(__float_as_uint(res) >> 16);
                }
                #pragma unroll
                for (int m = 0; m < 2; ++m) {
                    acc[m][q] = __builtin_amdgcn_mfma_f32_16x16x32_bf16(ahi[m], bhi, acc[m][q], 0, 0, 0);
                    acc[m][q] = __builtin_amdgcn_mfma_f32_16x16x32_bf16(alo[m], bhi, acc[m][q], 0, 0, 0);
                    acc[m][q] = __builtin_amdgcn_mfma_f32_16x16x32_bf16(ahi[m], blo, acc[m][q], 0, 0, 0);
                }
            }
        }

        // ---- cell update (i,f,g,o same lane) + h write (other buffer) + d partials ----
        #pragma unroll
        for (int m = 0; m < 2; ++m) {
            #pragma unroll
            for (int r = 0; r < 4; ++r) {
                float gi = acc[m][0][r];
                float gf = acc[m][1][r];
                float gg = acc[m][2][r];
                float go = acc[m][3][r];
                float c  = c_r[m][r];
                c = fmaf(sigf(gf), c, sigf(gi) * tanhf_fast(gg));
                c_r[m][r] = c;
                float h = sigf(go) * tanhf_fast(c);
                unsigned short hh = f2bf_rne(h);
                float hres = h - bf2f(hh);
                int haddr = (m * 8 + kc_w) * 512
                          + ((4 * l4 + r) + 16 * kwhi) * 8 + elemw;
                hhi[p ^ 1][haddr] = hh;
                hlo[p ^ 1][haddr] = f2bf_rne(hres);
                // d partial, reduced over the 16-lane j-group
                float s = h * wfc;
                s += __shfl_xor(s, 1);
                s += __shfl_xor(s, 2);
                s += __shfl_xor(s, 4);
                s += __shfl_xor(s, 8);
                if (l15 == 0) dpart[wave][16 * m + 4 * l4 + r] = s;
            }
        }
        __syncthreads();   // B_A: h(alt buf) + dpart visible

        // ---- final d = sum over 16 waves + b_fc ; feedback ----
        if (tid < BB) {
            float s = bfc;
            #pragma unroll
            for (int w = 0; w < 16; ++w) s += dpart[w][tid];
            inp_s[tid] = s;
            out[(size_t)(bbase + tid) * TLEN + t] = s;
        }
        __syncthreads();   // B_B: inp_s ready; weight/h reads of next step may begin
    }
}

extern "C" void kernel_launch(void* const* d_in, const int* in_sizes, int n_in,
                              void* d_out, int out_size, void* d_ws, size_t ws_size,
                              hipStream_t stream) {
    const float* x    = (const float*)d_in[0];
    const float* W_ih = (const float*)d_in[1];
    const float* W_hh = (const float*)d_in[2];
    const float* b_ih = (const float*)d_in[3];
    const float* b_hh = (const float*)d_in[4];
    const float* W_fc = (const float*)d_in[5];
    const float* b_fc = (const float*)d_in[6];
    float* out = (float*)d_out;

    const int BATCH   = in_sizes[0];        // 8192
    const int nblocks = BATCH / BB;         // 256 -> 1 block/CU

    lstm_mfma7<<<nblocks, NTHR, 0, stream>>>(
        x, W_ih, W_hh, b_ih, b_hh, W_fc, b_fc, out);
}

// Round 9
// 9961.407 us; speedup vs baseline: 2.9430x; 2.9430x over previous
//
#include <hip/hip_runtime.h>
#include <math.h>

#define HID   256
#define TLEN  512
#define NTHR  1024
#define GSIZE 8
#define NGRP  32
#define BBG   256            // batches per group

// h exchange: [NGRP][2 bufs][16 mt][8 kc][512] floats (A-fragment order)
#define HEX_PER_BUF (16 * 8 * 512)             // 65536 floats = 256 KiB
#define HEX_FLOATS  (NGRP * 2 * HEX_PER_BUF)   // 4,194,304 floats = 16 MiB
#define FLAGS_OFF   ((size_t)HEX_FLOATS * 4)
#define WS_NEEDED   (FLAGS_OFF + (size_t)NGRP * GSIZE * 4)

typedef __attribute__((ext_vector_type(8))) short short8;
typedef __attribute__((ext_vector_type(4))) float f32x4;

static __device__ __forceinline__ unsigned short f2bf_rne(float x) {
    unsigned int u = __float_as_uint(x);
    unsigned int r = (u + 0x7FFFu + ((u >> 16) & 1u)) >> 16;
    return (unsigned short)r;
}
static __device__ __forceinline__ float bf2f(unsigned short h) {
    return __uint_as_float(((unsigned int)h) << 16);
}
static __device__ __forceinline__ float sigf(float x) {
    return 1.0f / (1.0f + __expf(-x));
}
static __device__ __forceinline__ float tanhf_fast(float x) {
    return 1.0f - 2.0f / (1.0f + __expf(2.0f * x));
}

// two dwordx4 loads, L1-bypass (sc0), no wait — caller waits via vmcnt
static __device__ __forceinline__ void issue2_sc0(const float* p, float4& a, float4& b) {
    asm volatile("global_load_dwordx4 %0, %2, off sc0\n\t"
                 "global_load_dwordx4 %1, %2, off offset:16 sc0"
                 : "=&v"(a), "=&v"(b)
                 : "v"(p)
                 : "memory");
}

// ================= cooperative weight-stationary kernel =================
__global__ __launch_bounds__(NTHR, 4) void lstm_coop(
    const float* __restrict__ x,
    const float* __restrict__ W_ih,
    const float* __restrict__ W_hh,
    const float* __restrict__ b_ih,
    const float* __restrict__ b_hh,
    const float* __restrict__ W_fc,
    const float* __restrict__ b_fc,
    float* __restrict__ hexb,         // ws: h exchange
    unsigned int* __restrict__ flags, // ws: [NGRP][GSIZE], memset 0 per launch
    float* __restrict__ out)
{
    const int tid  = threadIdx.x;
    const int bid  = blockIdx.x;
    const int xcd  = bid & 7;          // assumes round-robin XCD mapping
    const int p    = (bid >> 3) & 7;   // producer index within group
    const int gsub = bid >> 6;         // 0..3
    const int g    = xcd * 4 + gsub;   // group 0..31 (XCD-local if mapping holds)
    const int bbase = g * BBG;
    const int mt   = tid >> 6;         // wave = M-tile (16 batches)
    const int lane = tid & 63;
    const int l15  = lane & 15;
    const int l4   = lane >> 4;

    __shared__ unsigned short whi_s[64 * 512];  // 64 KiB  B-frags hi
    __shared__ unsigned short wlo_s[64 * 512];  // 64 KiB  B-frags lo
    __shared__ float wfc_s[HID];

    // ---- stage this block's 128 gate-rows into LDS (split bf16, B-frag order) ----
    #pragma unroll
    for (int i = 0; i < 4; ++i) {
        int tile = mt * 4 + i;            // 0..63 = nt*8 + kc
        int nt = tile >> 3, kc = tile & 7;
        int q = nt >> 1, half = nt & 1;
        int grow = q * 256 + p * 32 + half * 16 + l15;
        int k0 = kc * 32 + l4 * 8;
        const float* src = W_hh + (size_t)grow * HID + k0;
        float4 wa = *(const float4*)src;
        float4 wb = *(const float4*)(src + 4);
        float ff[8] = {wa.x, wa.y, wa.z, wa.w, wb.x, wb.y, wb.z, wb.w};
        short8 hi8, lo8;
        #pragma unroll
        for (int e = 0; e < 8; ++e) {
            unsigned int u = __float_as_uint(ff[e]);
            hi8[e] = (short)(u >> 16);
            float res = ff[e] - __uint_as_float(u & 0xffff0000u);
            lo8[e] = (short)f2bf_rne(res);
        }
        *(short8*)&whi_s[tile * 512 + lane * 8] = hi8;
        *(short8*)&wlo_s[tile * 512 + lane * 8] = lo8;
    }
    if (tid < HID) wfc_s[tid] = W_fc[tid];

    // per-lane gate constants: nt = q*2+half -> grow
    float biasv[8], wihv[8];
    #pragma unroll
    for (int nt = 0; nt < 8; ++nt) {
        int grow = (nt >> 1) * 256 + p * 32 + (nt & 1) * 16 + l15;
        biasv[nt] = b_ih[grow] + b_hh[grow];
        wihv[nt]  = W_ih[grow];
    }
    const float bfc = b_fc[0];

    float c_r[2][4];
    #pragma unroll
    for (int half = 0; half < 2; ++half)
        #pragma unroll
        for (int r = 0; r < 4; ++r) c_r[half][r] = 0.0f;

    // h-store address constants: j = p*32 + half*16 + l15
    unsigned int* flg = flags + g * GSIZE;

    __syncthreads();

    // ================= step 0: gates = bias + x*wih (h=0) =================
    {
        float dreg[4];
        #pragma unroll
        for (int r = 0; r < 4; ++r) dreg[r] = x[bbase + mt * 16 + l4 * 4 + r];

        float* hb = hexb + ((size_t)g * 2 + 1) * HEX_PER_BUF;  // h(1) -> buf 1
        #pragma unroll
        for (int half = 0; half < 2; ++half) {
            #pragma unroll
            for (int r = 0; r < 4; ++r) {
                float gi = fmaf(dreg[r], wihv[0 + half], biasv[0 + half]);
                float gf = fmaf(dreg[r], wihv[2 + half], biasv[2 + half]);
                float gg = fmaf(dreg[r], wihv[4 + half], biasv[4 + half]);
                float go = fmaf(dreg[r], wihv[6 + half], biasv[6 + half]);
                float c = fmaf(sigf(gf), c_r[half][r], sigf(gi) * tanhf_fast(gg));
                c_r[half][r] = c;
                float h = sigf(go) * tanhf_fast(c);
                int lane_d = l4 * 4 + r + 16 * (half * 2 + (l15 >> 3));
                hb[(mt * 8 + p) * 512 + lane_d * 8 + (l15 & 7)] = h;
            }
        }
        __syncthreads();   // all stores ACKed in L2
        if (tid == 0)
            __hip_atomic_store(&flg[p], 1u, __ATOMIC_RELEASE, __HIP_MEMORY_SCOPE_AGENT);
    }

    // ================= steps 1..511 =================
    #pragma unroll 1
    for (int t = 1; t < TLEN; ++t) {
        // wait for all 8 shares of h(t)
        if (tid < GSIZE) {
            int guard = 0;
            while (__hip_atomic_load(&flg[tid], __ATOMIC_RELAXED, __HIP_MEMORY_SCOPE_AGENT)
                       < (unsigned int)t) {
                if (++guard > (1 << 20)) break;   // failsafe: never hang
            }
        }
        __syncthreads();

        const float* hb_r = hexb + ((size_t)g * 2 + (t & 1)) * HEX_PER_BUF
                          + (size_t)(mt * 8) * 512 + lane * 8;

        f32x4 acc[8];
        #pragma unroll
        for (int nt = 0; nt < 8; ++nt)
            #pragma unroll
            for (int r = 0; r < 4; ++r) acc[nt][r] = 0.0f;

        float dsum = 0.0f;
        float4 pf[2][2];
        issue2_sc0(hb_r, pf[0][0], pf[0][1]);

        #pragma unroll
        for (int kc = 0; kc < 8; ++kc) {
            if (kc < 7)
                issue2_sc0(hb_r + (kc + 1) * 512, pf[(kc + 1) & 1][0], pf[(kc + 1) & 1][1]);
            if (kc < 7) { asm volatile("s_waitcnt vmcnt(2)" ::: "memory"); }
            else        { asm volatile("s_waitcnt vmcnt(0)" ::: "memory"); }
            __builtin_amdgcn_sched_barrier(0);

            float4 va = pf[kc & 1][0], vb = pf[kc & 1][1];
            float ff[8] = {va.x, va.y, va.z, va.w, vb.x, vb.y, vb.z, vb.w};
            const float* wf = &wfc_s[kc * 32 + l4 * 8];
            short8 ahi, alo;
            #pragma unroll
            for (int e = 0; e < 8; ++e) {
                float f = ff[e];
                dsum = fmaf(f, wf[e], dsum);
                unsigned int u = __float_as_uint(f);
                ahi[e] = (short)(u >> 16);
                float res = f - __uint_as_float(u & 0xffff0000u);
                alo[e] = (short)f2bf_rne(res);
            }
            #pragma unroll
            for (int nt = 0; nt < 8; ++nt) {
                short8 bhi = *(const short8*)&whi_s[(nt * 8 + kc) * 512 + lane * 8];
                short8 blo = *(const short8*)&wlo_s[(nt * 8 + kc) * 512 + lane * 8];
                acc[nt] = __builtin_amdgcn_mfma_f32_16x16x32_bf16(ahi, bhi, acc[nt], 0, 0, 0);
                acc[nt] = __builtin_amdgcn_mfma_f32_16x16x32_bf16(alo, bhi, acc[nt], 0, 0, 0);
                acc[nt] = __builtin_amdgcn_mfma_f32_16x16x32_bf16(ahi, blo, acc[nt], 0, 0, 0);
            }
        }

        // d(t-1) = h(t)·wfc + bfc  (reduce over the 4 lanes sharing a batch)
        dsum += __shfl_xor(dsum, 16);
        dsum += __shfl_xor(dsum, 32);
        float d = dsum + bfc;
        if (p == 0 && lane < 16)
            out[(size_t)(bbase + mt * 16 + lane) * TLEN + (t - 1)] = d;
        float dreg[4];
        #pragma unroll
        for (int r = 0; r < 4; ++r) dreg[r] = __shfl(d, l4 * 4 + r);

        // cell update + h(t+1) store
        float* hb_w = hexb + ((size_t)g * 2 + ((t + 1) & 1)) * HEX_PER_BUF;
        #pragma unroll
        for (int half = 0; half < 2; ++half) {
            #pragma unroll
            for (int r = 0; r < 4; ++r) {
                float gi = acc[0 + half][r] + fmaf(dreg[r], wihv[0 + half], biasv[0 + half]);
                float gf = acc[2 + half][r] + fmaf(dreg[r], wihv[2 + half], biasv[2 + half]);
                float gg = acc[4 + half][r] + fmaf(dreg[r], wihv[4 + half], biasv[4 + half]);
                float go = acc[6 + half][r] + fmaf(dreg[r], wihv[6 + half], biasv[6 + half]);
                float c = fmaf(sigf(gf), c_r[half][r], sigf(gi) * tanhf_fast(gg));
                c_r[half][r] = c;
                float h = sigf(go) * tanhf_fast(c);
                int lane_d = l4 * 4 + r + 16 * (half * 2 + (l15 >> 3));
                hb_w[(mt * 8 + p) * 512 + lane_d * 8 + (l15 & 7)] = h;
            }
        }
        __syncthreads();   // drain stores to L2
        if (tid == 0)
            __hip_atomic_store(&flg[p], (unsigned int)(t + 1),
                               __ATOMIC_RELEASE, __HIP_MEMORY_SCOPE_AGENT);
    }

    // ================= epilogue: out[:,511] = h(512)·wfc + bfc =================
    {
        if (tid < GSIZE) {
            int guard = 0;
            while (__hip_atomic_load(&flg[tid], __ATOMIC_RELAXED, __HIP_MEMORY_SCOPE_AGENT)
                       < (unsigned int)TLEN) {
                if (++guard > (1 << 20)) break;
            }
        }
        __syncthreads();
        if (p == 0) {
            const float* hb_r = hexb + ((size_t)g * 2 + 0) * HEX_PER_BUF
                              + (size_t)(mt * 8) * 512 + lane * 8;
            float dsum = 0.0f;
            #pragma unroll
            for (int kc = 0; kc < 8; ++kc) {
                float4 va, vb;
                issue2_sc0(hb_r + kc * 512, va, vb);
                asm volatile("s_waitcnt vmcnt(0)" ::: "memory");
                __builtin_amdgcn_sched_barrier(0);
                float ff[8] = {va.x, va.y, va.z, va.w, vb.x, vb.y, vb.z, vb.w};
                const float* wf = &wfc_s[kc * 32 + l4 * 8];
                #pragma unroll
                for (int e = 0; e < 8; ++e) dsum = fmaf(ff[e], wf[e], dsum);
            }
            dsum += __shfl_xor(dsum, 16);
            dsum += __shfl_xor(dsum, 32);
            if (lane < 16)
                out[(size_t)(bbase + mt * 16 + lane) * TLEN + (TLEN - 1)] = dsum + bfc;
        }
    }
}

// ================= fallback (r8 kernel, needs no workspace) =================
#define BB 32
__global__ __launch_bounds__(NTHR, 4) void lstm_mfma7(
    const float* __restrict__ x, const float* __restrict__ W_ih,
    const float* __restrict__ W_hh, const float* __restrict__ b_ih,
    const float* __restrict__ b_hh, const float* __restrict__ W_fc,
    const float* __restrict__ b_fc, float* __restrict__ out)
{
    const int tid = threadIdx.x;
    const int wave = tid >> 6;
    const int lane = tid & 63;
    const int l15 = lane & 15;
    const int l4 = lane >> 4;
    const int bbase = blockIdx.x * BB;

    __shared__ unsigned short hhi[2][16 * 512];
    __shared__ unsigned short hlo[2][16 * 512];
    __shared__ float dpart[16][BB];
    __shared__ float inp_s[BB];

    for (int i = tid; i < 16 * 512; i += NTHR) { hhi[0][i] = 0; hlo[0][i] = 0; }
    if (tid < BB) inp_s[tid] = x[bbase + tid];

    float biasv[4], wihv[4];
    #pragma unroll
    for (int q = 0; q < 4; ++q) {
        int gg = 256 * q + 16 * wave + l15;
        biasv[q] = b_ih[gg] + b_hh[gg];
        wihv[q] = W_ih[gg];
    }
    const float wfc = W_fc[16 * wave + l15];
    const float bfc = b_fc[0];
    const float* __restrict__ wrow = W_hh + (size_t)(16 * wave + l15) * HID + l4 * 8;
    const int kc_w = wave >> 1;
    const int kwhi = (wave & 1) * 2 + (l15 >> 3);
    const int elemw = l15 & 7;

    float c_r[2][4];
    #pragma unroll
    for (int m = 0; m < 2; ++m)
        #pragma unroll
        for (int r = 0; r < 4; ++r) c_r[m][r] = 0.0f;
    __syncthreads();

    #pragma unroll 1
    for (int t = 0; t < TLEN; ++t) {
        const int p = t & 1;
        f32x4 acc[2][4];
        {
            float dv[2][4];
            #pragma unroll
            for (int m = 0; m < 2; ++m)
                #pragma unroll
                for (int r = 0; r < 4; ++r) dv[m][r] = inp_s[16 * m + 4 * l4 + r];
            #pragma unroll
            for (int m = 0; m < 2; ++m)
                #pragma unroll
                for (int q = 0; q < 4; ++q)
                    #pragma unroll
                    for (int r = 0; r < 4; ++r)
                        acc[m][q][r] = fmaf(dv[m][r], wihv[q], biasv[q]);
        }
        #pragma unroll
        for (int kc = 0; kc < 8; ++kc) {
            short8 ahi[2], alo[2];
            #pragma unroll
            for (int m = 0; m < 2; ++m) {
                int aoff = (m * 8 + kc) * 512 + lane * 8;
                ahi[m] = *(const short8*)&hhi[p][aoff];
                alo[m] = *(const short8*)&hlo[p][aoff];
            }
            #pragma unroll
            for (int q = 0; q < 4; ++q) {
                const float* src = wrow + (size_t)q * 256 * HID + kc * 32;
                float4 wa = *(const float4*)src;
                float4 wb = *(const float4*)(src + 4);
                float ff[8] = {wa.x, wa.y, wa.z, wa.w, wb.x, wb.y, wb.z, wb.w};
                short8 bhi, blo;
                #pragma unroll
                for (int e = 0; e < 8; ++e) {
                    unsigned int u = __float_as_uint(ff[e]);
                    bhi[e] = (short)(u >> 16);
                    float res = ff[e] - __uint_as_float(u & 0xffff0000u);
                    blo[e] = (short)(__float_as_uint(res) >> 16);
                }
                #pragma unroll
                for (int m = 0; m < 2; ++m) {
                    acc[m][q] = __builtin_amdgcn_mfma_f32_16x16x32_bf16(ahi[m], bhi, acc[m][q], 0, 0, 0);
                    acc[m][q] = __builtin_amdgcn_mfma_f32_16x16x32_bf16(alo[m], bhi, acc[m][q], 0, 0, 0);
                    acc[m][q] = __builtin_amdgcn_mfma_f32_16x16x32_bf16(ahi[m], blo, acc[m][q], 0, 0, 0);
                }
            }
        }
        #pragma unroll
        for (int m = 0; m < 2; ++m) {
            #pragma unroll
            for (int r = 0; r < 4; ++r) {
                float gi = acc[m][0][r];
                float gf = acc[m][1][r];
                float gg = acc[m][2][r];
                float go = acc[m][3][r];
                float c = fmaf(sigf(gf), c_r[m][r], sigf(gi) * tanhf_fast(gg));
                c_r[m][r] = c;
                float h = sigf(go) * tanhf_fast(c);
                unsigned short hh = f2bf_rne(h);
                float hres = h - bf2f(hh);
                int haddr = (m * 8 + kc_w) * 512 + ((4 * l4 + r) + 16 * kwhi) * 8 + elemw;
                hhi[p ^ 1][haddr] = hh;
                hlo[p ^ 1][haddr] = f2bf_rne(hres);
                float s = h * wfc;
                s += __shfl_xor(s, 1);
                s += __shfl_xor(s, 2);
                s += __shfl_xor(s, 4);
                s += __shfl_xor(s, 8);
                if (l15 == 0) dpart[wave][16 * m + 4 * l4 + r] = s;
            }
        }
        __syncthreads();
        if (tid < BB) {
            float s = bfc;
            #pragma unroll
            for (int w = 0; w < 16; ++w) s += dpart[w][tid];
            inp_s[tid] = s;
            out[(size_t)(bbase + tid) * TLEN + t] = s;
        }
        __syncthreads();
    }
}

extern "C" void kernel_launch(void* const* d_in, const int* in_sizes, int n_in,
                              void* d_out, int out_size, void* d_ws, size_t ws_size,
                              hipStream_t stream) {
    const float* x    = (const float*)d_in[0];
    const float* W_ih = (const float*)d_in[1];
    const float* W_hh = (const float*)d_in[2];
    const float* b_ih = (const float*)d_in[3];
    const float* b_hh = (const float*)d_in[4];
    const float* W_fc = (const float*)d_in[5];
    const float* b_fc = (const float*)d_in[6];
    float* out = (float*)d_out;

    const int BATCH = in_sizes[0];   // 8192

    if (ws_size >= WS_NEEDED) {
        unsigned int* flags = (unsigned int*)((char*)d_ws + FLAGS_OFF);
        hipMemsetAsync(flags, 0, (size_t)NGRP * GSIZE * 4, stream);
        lstm_coop<<<BATCH / BBG * GSIZE, NTHR, 0, stream>>>(
            x, W_ih, W_hh, b_ih, b_hh, W_fc, b_fc,
            (float*)d_ws, flags, out);
    } else {
        lstm_mfma7<<<BATCH / BB, NTHR, 0, stream>>>(
            x, W_ih, W_hh, b_ih, b_hh, W_fc, b_fc, out);
    }
}